// Round 7
// baseline (184.049 us; speedup 1.0000x reference)
//
#include <hip/hip_runtime.h>
#include <stdint.h>

#define NFREQ 256
#define NB 16
#define NT 4096
#define LOUT 1048832          // (4096+1)*256
#define TROWS 65              // legacy: t = j0-1 .. j0+63
#define TROW 132              // legacy: u32 per T row (528 B)
#define SROWS 4224            // specTs rows: t in [-8, 4216), 66 tiles of 64
#define ROW0 8                // specTs row index of t=0
#define KB_BYTES 262144
#define WS_NEED (KB_BYTES + (size_t)NB * SROWS * 512)

typedef __bf16 bf16;
typedef __bf16 bf16x8 __attribute__((ext_vector_type(8)));
typedef float floatx4 __attribute__((ext_vector_type(4)));

__device__ inline uint32_t f_as_u(float x) { union { float f; uint32_t u; } v; v.f = x; return v.u; }
__device__ inline uint32_t bf16r(float x) {     // RNE bf16 bits in low 16
    uint32_t u = f_as_u(x);
    return (u + 0x7fffu + ((u >> 16) & 1u)) >> 16;
}

// kbF frag-major: kbF[k'/32][n][k'%32] = Kb[n][k'],
//   Kb[n][f'] = (f'<256 ? K[n+256][f'] : K[n][f'-256]) / 128  (bf16 RNE)
__global__ __launch_bounds__(256) void build_kb(const float* __restrict__ ker,
                                                bf16* __restrict__ kbF) {
    int idx = blockIdx.x * 256 + threadIdx.x;   // 131072 total
    int n = idx >> 9, f = idx & 511;
    float v = (f < 256) ? ker[(n + 256) * 256 + f] : ker[n * 256 + (f - 256)];
    uint32_t rr = bf16r(v * 0.0078125f);
    union { uint16_t u; bf16 b; } o; o.u = (uint16_t)rr;
    kbF[((size_t)(f >> 5) * 256 + n) * 32 + (f & 31)] = o.b;
}

// specTs[b][t+8][ f ^ (((t+1)&7)<<3) ] = bf16(spec[b][f][t]), 0 outside t-range.
// Row-major t, 256 bf16 = 512 B per row; XOR-swizzle (T2, 16-B groups)
// pre-applied so gemm can global_load_lds rows LINEARLY and ds_read swizzled.
__global__ __launch_bounds__(256) void build_specT(const float* __restrict__ spec,
                                                   uint16_t* __restrict__ sT) {
    __shared__ __align__(16) uint16_t S[64 * 260];   // [t][f], pad 260 (bank-clean)
    const int b  = blockIdx.y;
    const int t0 = blockIdx.x * 64 - ROW0;           // rows t0 .. t0+63
    const int tid = threadIdx.x;
    const int tx = tid & 63, ty = tid >> 6;
    const float* sb = spec + (size_t)b * NFREQ * NT;
    const int t = t0 + tx;
    const bool tok = ((unsigned)t < (unsigned)NT);
    #pragma unroll 4
    for (int fq = 0; fq < 64; ++fq) {                // coalesced along t
        int f = fq * 4 + ty;
        float v = tok ? sb[(size_t)f * NT + t] : 0.0f;
        S[tx * 260 + f] = (uint16_t)bf16r(v);
    }
    __syncthreads();
    const int w = tid >> 6, lane = tid & 63;
    #pragma unroll 1
    for (int rr = 0; rr < 16; ++rr) {                // write swizzled rows
        int r = w * 16 + rr;
        int tg = t0 + r;
        int k = (tg + 1) & 7;
        uint2 v = *reinterpret_cast<const uint2*>(&S[r * 260 + lane * 4]);
        uint16_t* drow = sT + ((size_t)b * SROWS + (tg + ROW0)) * 256;
        int dst = (((lane >> 1) ^ k) << 3) + ((lane & 1) << 2);
        *reinterpret_cast<uint2*>(&drow[dst]) = v;
    }
}

// FAST gemm: A-tile staged via global_load_lds width=16 (deep in-flight, no
// dest VGPRs, no VALU pack); T already bf16 + swizzled in specTs. LDS 33.8 KB
// -> 4 blocks/CU. B-frags stream global->VGPR from frag-major kbF (L2-hot).
__global__ __launch_bounds__(256, 4) void imdct_gemm_f(const uint16_t* __restrict__ sT,
                                                       const bf16* __restrict__ kbF,
                                                       float* __restrict__ out) {
    __shared__ __align__(16) uint16_t T[66 * 256];   // 33792 B (row 65 = overshoot)
    const int jt = blockIdx.x, b = blockIdx.y;       // jt 0..64
    const int tid = threadIdx.x, lane = tid & 63, w = tid >> 6;
    const int j0 = jt * 64;
    const char* sB = (const char*)(sT + ((size_t)b * SROWS + (size_t)(j0 - 1 + ROW0)) * 256);

    // ---- stage rows t = j0-1 .. j0+64 (66 rows, 33 x 1KB insts) ----
    {
        const char* gp0 = sB + lane * 16;
        #pragma unroll 1
        for (int r2 = w; r2 < 33; r2 += 4) {
            __builtin_amdgcn_global_load_lds(
                (const __attribute__((address_space(1))) uint32_t*)(gp0 + r2 * 1024),
                (__attribute__((address_space(3))) uint32_t*)((char*)T + r2 * 1024),
                16, 0, 0);
        }
        asm volatile("s_waitcnt vmcnt(0)" ::: "memory");
    }
    __syncthreads();                                 // the ONLY barrier

    const int row16 = lane & 15, q = lane >> 4;
    floatx4 acc[4][4] = {};
    const char* Tb = (const char*)T;
    const bf16* kbw = kbF + (size_t)w * 64 * 32 + (row16 * 32 + q * 8);
    const int swz0 = (row16 & 7) << 4, swz1 = ((row16 + 1) & 7) << 4;

    #pragma unroll 1
    for (int kki = 0; kki < 8; ++kki) {              // rolled (I$-small)
        const int toff = kki >> 2;
        const int kbyte = (kki & 3) * 128;
        const char* ta = Tb + (size_t)(row16 + toff) * 512;
        const int sz = toff ? swz1 : swz0;
        const bf16* kb2 = kbw + (size_t)kki * 16384;
        #pragma unroll
        for (int ks = 0; ks < 2; ++ks) {
            bf16x8 af[4], bfr[4];
            #pragma unroll
            for (int jn = 0; jn < 4; ++jn)
                bfr[jn] = *reinterpret_cast<const bf16x8*>(kb2 + (size_t)ks * 8192 + jn * 512);
            const int col = (kbyte + ks * 64 + q * 16) ^ sz;
            #pragma unroll
            for (int i = 0; i < 4; ++i)
                af[i] = *reinterpret_cast<const bf16x8*>(ta + i * 8192 + col);
            #pragma unroll
            for (int i = 0; i < 4; ++i)
                #pragma unroll
                for (int jn = 0; jn < 4; ++jn)
                    acc[i][jn] = __builtin_amdgcn_mfma_f32_16x16x32_bf16(af[i], bfr[jn], acc[i][jn], 0, 0, 0);
        }
    }

    // epilogue: C/D layout col=lane&15 (n), row=q*4+e (j within 16)
    #pragma unroll
    for (int i = 0; i < 4; ++i) {
        #pragma unroll
        for (int e = 0; e < 4; ++e) {
            int j = j0 + i * 16 + q * 4 + e;
            if (j <= 4096) {
                float* orow = out + (size_t)b * LOUT + (size_t)j * 256 + w * 64;
                #pragma unroll
                for (int jn = 0; jn < 4; ++jn)
                    orow[jn * 16 + row16] = acc[i][jn][e];
            }
        }
    }
}

// LEGACY gemm (round-6, proven 58-62us) - used when ws is too small for specTs.
__global__ __launch_bounds__(256, 4) void imdct_gemm(const float* __restrict__ spec,
                                                     const bf16* __restrict__ kbF,
                                                     float* __restrict__ out) {
    __shared__ uint32_t Tt[TROWS * TROW];
    const int jt = blockIdx.x;
    const int b  = blockIdx.y;
    const int tid = threadIdx.x, lane = tid & 63, w = tid >> 6;
    const int j0 = jt * 64;
    const float* sb = spec + (size_t)b * NFREQ * NT;
    {
        const int lpar = lane & 1, lt = lane >> 1;
        const int fpw = w * 32;
        #pragma unroll 1
        for (int rb = 0; rb < 4; ++rb) {
            const int tc = rb >> 1;
            const int fh = (rb & 1) * 16;
            const int t  = j0 - 1 + tc * 32 + lt;
            const bool tok = ((unsigned)t < (unsigned)NT);
            const float* pb = sb + (size_t)((fpw + fh) * 2 + lpar) * NT + t;
            float v[16];
            #pragma unroll
            for (int i = 0; i < 16; ++i)
                v[i] = tok ? pb[(size_t)i * 2 * NT] : 0.0f;
            const int tl = tc * 32 + lt;
            uint32_t* dst = &Tt[tl * TROW + fpw + fh];
            #pragma unroll
            for (int i = 0; i < 16; i += 4) {
                uint32_t pk[4];
                #pragma unroll
                for (int u = 0; u < 4; ++u) {
                    uint32_t h = bf16r(v[i + u]);
                    uint32_t o = (uint32_t)__shfl_xor((int)h, 1);
                    pk[u] = (h & 0xffffu) | (o << 16);
                }
                if (lpar == 0) {
                    uint4 q4; q4.x = pk[0]; q4.y = pk[1]; q4.z = pk[2]; q4.w = pk[3];
                    *reinterpret_cast<uint4*>(dst + i) = q4;
                }
            }
        }
        {
            int f = w * 64 + lane;
            int te = j0 + 63;
            float v = ((unsigned)te < (unsigned)NT) ? sb[(size_t)f * NT + te] : 0.0f;
            uint32_t h = bf16r(v); uint32_t o = (uint32_t)__shfl_xor((int)h, 1);
            if (lpar == 0) Tt[64 * TROW + w * 32 + lt] = (h & 0xffffu) | (o << 16);
        }
    }
    __syncthreads();
    const int row16 = lane & 15, q = lane >> 4;
    floatx4 acc[4][4] = {};
    const uint8_t* Tb = reinterpret_cast<const uint8_t*>(Tt);
    const bf16* kbw = kbF + (size_t)w * 64 * 32 + (row16 * 32 + q * 8);
    #pragma unroll 1
    for (int kki = 0; kki < 8; ++kki) {
        const int toff = kki >> 2;
        const int kbyte = (kki & 3) * 128;
        const uint8_t* ta = Tb + (size_t)(row16 + toff) * 528 + kbyte + q * 16;
        const bf16* kb2 = kbw + (size_t)kki * 16384;
        #pragma unroll
        for (int ks = 0; ks < 2; ++ks) {
            bf16x8 af[4], bfr[4];
            #pragma unroll
            for (int jn = 0; jn < 4; ++jn)
                bfr[jn] = *reinterpret_cast<const bf16x8*>(kb2 + (size_t)ks * 8192 + jn * 512);
            #pragma unroll
            for (int i = 0; i < 4; ++i)
                af[i] = *reinterpret_cast<const bf16x8*>(ta + ks * 64 + i * 8448);
            #pragma unroll
            for (int i = 0; i < 4; ++i)
                #pragma unroll
                for (int jn = 0; jn < 4; ++jn)
                    acc[i][jn] = __builtin_amdgcn_mfma_f32_16x16x32_bf16(af[i], bfr[jn], acc[i][jn], 0, 0, 0);
        }
    }
    #pragma unroll
    for (int i = 0; i < 4; ++i) {
        #pragma unroll
        for (int e = 0; e < 4; ++e) {
            int j = j0 + i * 16 + q * 4 + e;
            if (j <= 4096) {
                float* orow = out + (size_t)b * LOUT + (size_t)j * 256 + w * 64;
                #pragma unroll
                for (int jn = 0; jn < 4; ++jn)
                    orow[jn * 16 + row16] = acc[i][jn][e];
            }
        }
    }
}

extern "C" void kernel_launch(void* const* d_in, const int* in_sizes, int n_in,
                              void* d_out, int out_size, void* d_ws, size_t ws_size,
                              hipStream_t stream) {
    const float* spec = (const float*)d_in[0];   // [16][1][256][4096] fp32
    const float* ker  = (const float*)d_in[1];   // [512][256] fp32
    float* out = (float*)d_out;                  // [16][1048832] fp32

    bf16* kbF = (bf16*)d_ws;                     // 256 KB
    build_kb<<<512, 256, 0, stream>>>(ker, kbF);

    if (ws_size >= WS_NEED) {
        // fast path: pre-transposed swizzled bf16 spec + gload_lds staging
        uint16_t* sTt = (uint16_t*)((char*)d_ws + KB_BYTES);
        build_specT<<<dim3(66, NB), 256, 0, stream>>>(spec, sTt);
        imdct_gemm_f<<<dim3(65, NB), 256, 0, stream>>>(sTt, kbF, out);
    } else {
        // legacy round-6 path (proven): ws too small for specTs
        imdct_gemm<<<dim3(65, NB), 256, 0, stream>>>(spec, kbF, out);
    }
}

// Round 8
// 145.708 us; speedup vs baseline: 1.2631x; 1.2631x over previous
//
#include <hip/hip_runtime.h>
#include <stdint.h>

#define NFREQ 256
#define NB 16
#define NT 4096
#define LOUT 1048832          // (4096+1)*256
#define TROWS 65              // legacy: t = j0-1 .. j0+63
#define TROW 132              // legacy: u32 per T row (528 B)
#define SROWS 4224            // specTs rows: t in [-8, 4216)
#define ROW0 8                // specTs row index of t=0
#define KB_BYTES 262144
#define WS_NEED (KB_BYTES + (size_t)NB * SROWS * 512)

typedef __bf16 bf16;
typedef __bf16 bf16x8 __attribute__((ext_vector_type(8)));
typedef float floatx4 __attribute__((ext_vector_type(4)));

__device__ inline uint32_t f_as_u(float x) { union { float f; uint32_t u; } v; v.f = x; return v.u; }
__device__ inline uint32_t bf16r(float x) {     // RNE bf16 bits in low 16
    uint32_t u = f_as_u(x);
    return (u + 0x7fffu + ((u >> 16) & 1u)) >> 16;
}

// kbF frag-major: kbF[k'/32][n][k'%32] = Kb[n][k'],
//   Kb[n][f'] = (f'<256 ? K[n+256][f'] : K[n][f'-256]) / 128  (bf16 RNE)
__global__ __launch_bounds__(256) void build_kb(const float* __restrict__ ker,
                                                bf16* __restrict__ kbF) {
    int idx = blockIdx.x * 256 + threadIdx.x;   // 131072 total
    int n = idx >> 9, f = idx & 511;
    float v = (f < 256) ? ker[(n + 256) * 256 + f] : ker[n * 256 + (f - 256)];
    uint32_t rr = bf16r(v * 0.0078125f);
    union { uint16_t u; bf16 b; } o; o.u = (uint16_t)rr;
    kbF[((size_t)(f >> 5) * 256 + n) * 32 + (f & 31)] = o.b;
}

// specTs[b][t+8][ f ^ (((t+1)&7)<<3) ] = bf16(spec[b][f][t]), 0 outside range.
// v2: tile [64 f x 256 t] per block; 16 independent float4 loads per thread
// issued as ONE burst (no interleaved LDS dependence -> deep in-flight);
// S holds the tile [256 t][66 u16] with an internal group-XOR swizzle
// (key (tl>>2)&7) so both write (u16 scalar) and read (4x b32) are ~2-way;
// stores are full uint4 per 16-B output group with the T2 swizzle g^k.
__global__ __launch_bounds__(256) void build_specT(const float* __restrict__ spec,
                                                   uint16_t* __restrict__ sT) {
    __shared__ __align__(16) uint16_t S[256 * 66];   // 33792 B -> 4 blocks/CU
    const int b  = blockIdx.z;
    const int f0 = blockIdx.y * 64;                  // f quarter
    const int t0 = blockIdx.x * 256 - ROW0;          // t rows t0 .. t0+255
    const int tid = threadIdx.x, lane = tid & 63, w = tid >> 6;
    const float* sb = spec + (size_t)b * NFREQ * NT;

    // ---- load burst: lane -> (fi = lane>>2, tq = lane&3); 16 float4 each ----
    const int fi = lane >> 2, tq = lane & 3;
    const int fl = w * 16 + fi;                      // local f 0..63
    const float* fp = sb + (size_t)(f0 + fl) * NT;
    floatx4 v[16];
    #pragma unroll
    for (int i = 0; i < 16; ++i) {                   // all independent, in flight
        int t = t0 + tq * 4 + i * 16;                // t % 4 == 0 always
        if ((unsigned)t < (unsigned)NT)
            v[i] = *reinterpret_cast<const floatx4*>(fp + t);
        else
            v[i] = (floatx4){0.f, 0.f, 0.f, 0.f};
    }
    // ---- convert + LDS write (internal swizzle: col = fl ^ (((tl>>2)&7)<<3)) ----
    #pragma unroll
    for (int i = 0; i < 16; ++i) {
        #pragma unroll
        for (int d = 0; d < 4; ++d) {
            int tl = tq * 4 + i * 16 + d;            // local t 0..255
            int c = fl ^ (((tl >> 2) & 7) << 3);
            S[tl * 66 + c] = (uint16_t)bf16r(v[i][d]);
        }
    }
    __syncthreads();

    // ---- store: 8 passes, one uint4 (16 B = one swizzle group) per thread ----
    #pragma unroll 1
    for (int p = 0; p < 8; ++p) {
        int idx = p * 256 + tid;                     // 0..2047
        int r = idx >> 3, g = idx & 7;               // local row, local group
        int tg = t0 + r;
        if (tg + ROW0 < SROWS) {
            int kk = (r >> 2) & 7;                   // S internal key
            int gr = (g ^ kk) * 8;
            uint32_t d0 = *reinterpret_cast<const uint32_t*>(&S[r * 66 + gr + 0]);
            uint32_t d1 = *reinterpret_cast<const uint32_t*>(&S[r * 66 + gr + 2]);
            uint32_t d2 = *reinterpret_cast<const uint32_t*>(&S[r * 66 + gr + 4]);
            uint32_t d3 = *reinterpret_cast<const uint32_t*>(&S[r * 66 + gr + 6]);
            int k = (tg + 1) & 7;                    // output T2 key (global t)
            uint16_t* drow = sT + ((size_t)b * SROWS + (tg + ROW0)) * 256 + f0;
            uint4 val; val.x = d0; val.y = d1; val.z = d2; val.w = d3;
            *reinterpret_cast<uint4*>(drow + ((g ^ k) << 3)) = val;
        }
    }
}

// FAST gemm: A-tile staged via global_load_lds width=16 (deep in-flight, no
// dest VGPRs, no VALU pack); T already bf16 + swizzled in specTs.
// v2: B-fragment register ping-pong (bP/bQ) so chunk c+1's 4 global loads
// stay in flight under chunk c's 16 MFMAs (counted vmcnt, no drain).
__global__ __launch_bounds__(256, 4) void imdct_gemm_f(const uint16_t* __restrict__ sT,
                                                       const bf16* __restrict__ kbF,
                                                       float* __restrict__ out) {
    __shared__ __align__(16) uint16_t T[66 * 256];   // 33792 B -> 4 blocks/CU
    const int jt = blockIdx.x, b = blockIdx.y;       // jt 0..64
    const int tid = threadIdx.x, lane = tid & 63, w = tid >> 6;
    const int j0 = jt * 64;
    const char* sB = (const char*)(sT + ((size_t)b * SROWS + (size_t)(j0 - 1 + ROW0)) * 256);

    // ---- stage rows t = j0-1 .. j0+64 (66 rows, 33 x 1KB insts) ----
    {
        const char* gp0 = sB + lane * 16;
        #pragma unroll 1
        for (int r2 = w; r2 < 33; r2 += 4) {
            __builtin_amdgcn_global_load_lds(
                (const __attribute__((address_space(1))) uint32_t*)(gp0 + r2 * 1024),
                (__attribute__((address_space(3))) uint32_t*)((char*)T + r2 * 1024),
                16, 0, 0);
        }
        asm volatile("s_waitcnt vmcnt(0)" ::: "memory");
    }
    __syncthreads();                                 // the ONLY barrier

    const int row16 = lane & 15, q = lane >> 4;
    floatx4 acc[4][4] = {};
    const char* Tb = (const char*)T;
    const bf16* kbw = kbF + (size_t)w * 64 * 32 + (row16 * 32 + q * 8);

#define LOADB_(dst, c) { \
    _Pragma("unroll") \
    for (int jn_ = 0; jn_ < 4; ++jn_) \
        dst[jn_] = *reinterpret_cast<const bf16x8*>(kbw + (size_t)(c) * 8192 + jn_ * 512); }
#define ACHUNK_(c, bsel) { \
    int tr_ = row16 + ((c) >> 3); \
    const char* ta_ = Tb + (size_t)tr_ * 512; \
    int col_ = (((c) & 7) * 64 + q * 16) ^ ((tr_ & 7) << 4); \
    bf16x8 af_[4]; \
    _Pragma("unroll") \
    for (int i_ = 0; i_ < 4; ++i_) \
        af_[i_] = *reinterpret_cast<const bf16x8*>(ta_ + i_ * 8192 + col_); \
    _Pragma("unroll") \
    for (int i_ = 0; i_ < 4; ++i_) \
        _Pragma("unroll") \
        for (int jn_ = 0; jn_ < 4; ++jn_) \
            acc[i_][jn_] = __builtin_amdgcn_mfma_f32_16x16x32_bf16(af_[i_], bsel[jn_], acc[i_][jn_], 0, 0, 0); }

    bf16x8 bP[4], bQ[4];
    LOADB_(bP, 0);
    #pragma unroll 1
    for (int cc = 0; cc < 8; ++cc) {                 // rolled (I$-small), ping-pong
        LOADB_(bQ, cc * 2 + 1);                      // prefetch odd chunk
        ACHUNK_(cc * 2, bP);                         // compute even (bP resident)
        if (cc < 7) LOADB_(bP, cc * 2 + 2);          // prefetch next even
        ACHUNK_(cc * 2 + 1, bQ);                     // compute odd
    }
#undef LOADB_
#undef ACHUNK_

    // epilogue: C/D layout col=lane&15 (n), row=q*4+e (j within 16)
    #pragma unroll
    for (int i = 0; i < 4; ++i) {
        #pragma unroll
        for (int e = 0; e < 4; ++e) {
            int j = j0 + i * 16 + q * 4 + e;
            if (j <= 4096) {
                float* orow = out + (size_t)b * LOUT + (size_t)j * 256 + w * 64;
                #pragma unroll
                for (int jn = 0; jn < 4; ++jn)
                    orow[jn * 16 + row16] = acc[i][jn][e];
            }
        }
    }
}

// LEGACY gemm (round-6, proven) - used when ws is too small for specTs.
__global__ __launch_bounds__(256, 4) void imdct_gemm(const float* __restrict__ spec,
                                                     const bf16* __restrict__ kbF,
                                                     float* __restrict__ out) {
    __shared__ uint32_t Tt[TROWS * TROW];
    const int jt = blockIdx.x;
    const int b  = blockIdx.y;
    const int tid = threadIdx.x, lane = tid & 63, w = tid >> 6;
    const int j0 = jt * 64;
    const float* sb = spec + (size_t)b * NFREQ * NT;
    {
        const int lpar = lane & 1, lt = lane >> 1;
        const int fpw = w * 32;
        #pragma unroll 1
        for (int rb = 0; rb < 4; ++rb) {
            const int tc = rb >> 1;
            const int fh = (rb & 1) * 16;
            const int t  = j0 - 1 + tc * 32 + lt;
            const bool tok = ((unsigned)t < (unsigned)NT);
            const float* pb = sb + (size_t)((fpw + fh) * 2 + lpar) * NT + t;
            float v[16];
            #pragma unroll
            for (int i = 0; i < 16; ++i)
                v[i] = tok ? pb[(size_t)i * 2 * NT] : 0.0f;
            const int tl = tc * 32 + lt;
            uint32_t* dst = &Tt[tl * TROW + fpw + fh];
            #pragma unroll
            for (int i = 0; i < 16; i += 4) {
                uint32_t pk[4];
                #pragma unroll
                for (int u = 0; u < 4; ++u) {
                    uint32_t h = bf16r(v[i + u]);
                    uint32_t o = (uint32_t)__shfl_xor((int)h, 1);
                    pk[u] = (h & 0xffffu) | (o << 16);
                }
                if (lpar == 0) {
                    uint4 q4; q4.x = pk[0]; q4.y = pk[1]; q4.z = pk[2]; q4.w = pk[3];
                    *reinterpret_cast<uint4*>(dst + i) = q4;
                }
            }
        }
        {
            int f = w * 64 + lane;
            int te = j0 + 63;
            float v = ((unsigned)te < (unsigned)NT) ? sb[(size_t)f * NT + te] : 0.0f;
            uint32_t h = bf16r(v); uint32_t o = (uint32_t)__shfl_xor((int)h, 1);
            if (lpar == 0) Tt[64 * TROW + w * 32 + lt] = (h & 0xffffu) | (o << 16);
        }
    }
    __syncthreads();
    const int row16 = lane & 15, q = lane >> 4;
    floatx4 acc[4][4] = {};
    const uint8_t* Tb = reinterpret_cast<const uint8_t*>(Tt);
    const bf16* kbw = kbF + (size_t)w * 64 * 32 + (row16 * 32 + q * 8);
    #pragma unroll 1
    for (int kki = 0; kki < 8; ++kki) {
        const int toff = kki >> 2;
        const int kbyte = (kki & 3) * 128;
        const uint8_t* ta = Tb + (size_t)(row16 + toff) * 528 + kbyte + q * 16;
        const bf16* kb2 = kbw + (size_t)kki * 16384;
        #pragma unroll
        for (int ks = 0; ks < 2; ++ks) {
            bf16x8 af[4], bfr[4];
            #pragma unroll
            for (int jn = 0; jn < 4; ++jn)
                bfr[jn] = *reinterpret_cast<const bf16x8*>(kb2 + (size_t)ks * 8192 + jn * 512);
            #pragma unroll
            for (int i = 0; i < 4; ++i)
                af[i] = *reinterpret_cast<const bf16x8*>(ta + ks * 64 + i * 8448);
            #pragma unroll
            for (int i = 0; i < 4; ++i)
                #pragma unroll
                for (int jn = 0; jn < 4; ++jn)
                    acc[i][jn] = __builtin_amdgcn_mfma_f32_16x16x32_bf16(af[i], bfr[jn], acc[i][jn], 0, 0, 0);
        }
    }
    #pragma unroll
    for (int i = 0; i < 4; ++i) {
        #pragma unroll
        for (int e = 0; e < 4; ++e) {
            int j = j0 + i * 16 + q * 4 + e;
            if (j <= 4096) {
                float* orow = out + (size_t)b * LOUT + (size_t)j * 256 + w * 64;
                #pragma unroll
                for (int jn = 0; jn < 4; ++jn)
                    orow[jn * 16 + row16] = acc[i][jn][e];
            }
        }
    }
}

extern "C" void kernel_launch(void* const* d_in, const int* in_sizes, int n_in,
                              void* d_out, int out_size, void* d_ws, size_t ws_size,
                              hipStream_t stream) {
    const float* spec = (const float*)d_in[0];   // [16][1][256][4096] fp32
    const float* ker  = (const float*)d_in[1];   // [512][256] fp32
    float* out = (float*)d_out;                  // [16][1048832] fp32

    bf16* kbF = (bf16*)d_ws;                     // 256 KB
    build_kb<<<512, 256, 0, stream>>>(ker, kbF);

    if (ws_size >= WS_NEED) {
        // fast path: pre-transposed swizzled bf16 spec + gload_lds staging
        uint16_t* sTt = (uint16_t*)((char*)d_ws + KB_BYTES);
        build_specT<<<dim3(17, 4, NB), 256, 0, stream>>>(spec, sTt);
        imdct_gemm_f<<<dim3(65, NB), 256, 0, stream>>>(sTt, kbF, out);
    } else {
        // legacy round-6 path (proven): ws too small for specTs
        imdct_gemm<<<dim3(65, NB), 256, 0, stream>>>(spec, kbF, out);
    }
}